// Round 8
// baseline (130.603 us; speedup 1.0000x reference)
//
#include <hip/hip_runtime.h>

#define B_SZ   32
#define T_LEN  160000
#define NFFT   1024
#define HOP    320
#define FRAMES 501
#define NBINS  513
#define PADL   512

#define MROWS_BF  1024                    // interleaved cos/sin rows (bins 0..511); row 1024 = w512
#define XP_STRIDE 164864                  // padded per-batch xp length (elements)
#define WS_XP_OFF (1025 * NFFT)           // ushort-element offset of xp region in ws
#define XP_G8_PB  (XP_STRIDE / 8)         // 20608 8-elem groups per batch

// prep-kernel block ranges: [0,512) basis rows 0..1023 | 512: w512 row | xp convert
#define PB_BASIS  512
#define PB_XP     2576
#define PREP_BLOCKS (PB_BASIS + 1 + PB_XP)

// K-trim: Hann window (WIN=800) is zero outside k in [112,912) -> basis cols
// there are exactly 0.0. Cover with 32-aligned range [96,928): 26 tiles of 32.
#define KT0  96
#define NKT  26

#define LBUF 12288                        // elems per LDS buffer: A 8192 + B 4096

typedef __bf16 bf16x8  __attribute__((ext_vector_type(8)));
typedef float  floatx4 __attribute__((ext_vector_type(4)));

__device__ __forceinline__ unsigned short f2bf(float f) {
    unsigned u = __builtin_bit_cast(unsigned, f);
    u += 0x7FFFu + ((u >> 16) & 1u);      // round-to-nearest-even
    return (unsigned short)(u >> 16);
}

__device__ __forceinline__ void gl_lds16(const void* g, void* l) {
    __builtin_amdgcn_global_load_lds(
        (const __attribute__((address_space(1))) unsigned int*)g,
        (__attribute__((address_space(3))) unsigned int*)l, 16, 0, 0);
}

// ---- prep: pure-bandwidth converts only (bin512 computed inside the GEMM) ----
__global__ void stft_prep(const float* __restrict__ x,
                          const float* __restrict__ basis,
                          unsigned short* __restrict__ basisb,
                          unsigned short* __restrict__ xpb,
                          float* __restrict__ out) {
    const int blk = blockIdx.x;
    const int tid = threadIdx.x;

    if (blk < PB_BASIS) {
        const int gid = blk * 256 + tid;          // 8 elems per thread, exact cover
        const int row = gid >> 7;                 // 0..1023
        const int col = (gid & 127) * 8;
        const int j = row >> 1, c = row & 1;
        const float* src = basis + (size_t)(j + c * NBINS) * NFFT + col;
        const float4 v0 = *(const float4*)(src);
        const float4 v1 = *(const float4*)(src + 4);
        ushort4 o0, o1;
        o0.x = f2bf(v0.x); o0.y = f2bf(v0.y); o0.z = f2bf(v0.z); o0.w = f2bf(v0.w);
        o1.x = f2bf(v1.x); o1.y = f2bf(v1.y); o1.z = f2bf(v1.z); o1.w = f2bf(v1.w);
        unsigned short* d = basisb + ((size_t)row << 10) + col;
        *(ushort4*)(d)     = o0;
        *(ushort4*)(d + 4) = o1;
    } else if (blk == PB_BASIS) {
        // w512 row: bf16 of basis row 512 (windowed cos_512); 256 thr x 4 elems
        const float4 v = *(const float4*)(basis + (size_t)512 * NFFT + tid * 4);
        ushort4 o;
        o.x = f2bf(v.x); o.y = f2bf(v.y); o.z = f2bf(v.z); o.w = f2bf(v.w);
        *(ushort4*)(basisb + ((size_t)1024 << 10) + tid * 4) = o;
    } else {
        const int i   = (blk - PB_BASIS - 1) * 256 + tid;   // 0..659455, exact cover
        const int b   = i / XP_G8_PB;
        const int pos = (i - b * XP_G8_PB) * 8;         // boundaries (512,160512) are %8==0
        ushort4 o0 = {0,0,0,0}, o1 = {0,0,0,0};
        if (pos >= PADL && pos < T_LEN + PADL) {
            const float* src = x + (size_t)b * T_LEN + (pos - PADL);
            const float4 v0 = *(const float4*)(src);
            const float4 v1 = *(const float4*)(src + 4);
            o0.x = f2bf(v0.x); o0.y = f2bf(v0.y); o0.z = f2bf(v0.z); o0.w = f2bf(v0.w);
            o1.x = f2bf(v1.x); o1.y = f2bf(v1.y); o1.z = f2bf(v1.z); o1.w = f2bf(v1.w);
        }
        unsigned short* d = xpb + (size_t)b * XP_STRIDE + pos;
        *(ushort4*)(d)     = o0;
        *(ushort4*)(d + 4) = o1;
    }
}

// ---- MFMA GEMM v8 = v7b loop, persistent 2-tile blocks.
// 256 blocks (1/CU), each processes frame-tiles fg0 and fg0+256 sequentially
// with the identical proven phase loop (3 rotating LDS bufs, BK=32, counted
// vmcnt(3), XOR swizzle, koff stagger, fused bin512). Tile-1's 33MB of output
// stores are issued mid-kernel and drain under tile-2's K-loop (HBM idle
// headroom), leaving only tile-2's 33MB as the end-of-kernel drain.
// Pass transition ledger: barrier (all phase-25 frag reads done; each wave's
// reads are lgkm-drained before its own MFMA) -> vmcnt(0) (wrap-garbage DMA
// landed; same-dest DMA completion is unordered so this MUST precede restage)
// -> restage tiles koff,koff+1 of pass 2 (per-thread dest slots disjoint)
// -> epilogue-1 stores (register-only; overlap the restage latency)
// -> vmcnt(0) -> barrier  => pass-2 entry invariant identical to prologue.
__launch_bounds__(512, 2)
__global__ void stft_mfma_kernel(const unsigned short* __restrict__ basisb,
                                 const unsigned short* __restrict__ xpb,
                                 float* __restrict__ out) {
    __shared__ unsigned short lds[3 * LBUF];   // 72 KB: per buf A[0..8191], B[8192..12287]
    __shared__ unsigned short w512l[1024];     // w512 row, global k in [0,1024)

    const int tid  = threadIdx.x;
    const int lane = tid & 63;
    const int w    = tid >> 6;        // wave 0..7
    const int wm   = w & 3;           // 64-row quarter of 256
    const int wn   = w >> 2;          // 64-frame half of 128
    const int r0   = lane & 15;
    const int quad = lane >> 4;
    // swizzled 16B-slot within a 64-B row: slot = quad ^ ((row>>1)&3)
    const int ce   = (quad ^ ((r0 >> 1) & 3)) * 8;

    const int b   = blockIdx.x;                 // batch fastest -> XCD = b%8
    const int fg0 = blockIdx.y * 128;           // frame tile base (0,128); pass adds +256
    const int mg0 = blockIdx.z * 256;           // row tile base (0..768)
    const unsigned short* xpbb = xpb + (size_t)b * XP_STRIDE;
    const int koff = (((b >> 3) ^ blockIdx.y ^ blockIdx.z) & 1) * 13;
    const bool do512 = (mg0 == 0) && (wm == 0);  // wave-uniform

    // staging: A 256x32 (16KB, 2 loads/thr), B 128x32 (8KB, 1 load/thr).
    // LDS dest linear; global source column pre-swizzled (same involution as reads).
    const int i0 = tid, i1 = 512 + tid;
    const int rowA0 = i0 >> 2, rowA1 = i1 >> 2;        // 0..127, 128..255
    const int rowB  = tid >> 2;                        // 0..127
    const int csA0 = ((i0 & 3) ^ ((rowA0 >> 1) & 3)) * 8;
    const int csA1 = ((i1 & 3) ^ ((rowA1 >> 1) & 3)) * 8;
    const int csB  = ((tid & 3) ^ ((rowB >> 1) & 3)) * 8;
    const unsigned short* arow0 = basisb + ((size_t)(mg0 + rowA0) << 10) + csA0;
    const unsigned short* arow1 = basisb + ((size_t)(mg0 + rowA1) << 10) + csA1;
    const unsigned short* brow0 = xpbb + (size_t)(fg0 + rowB) * HOP + csB;

#define STAGE(kk, sto, BP) do {                                     \
    const int ko_ = KT0 + (kk) * 32;                                \
    gl_lds16(arow0 + ko_, &lds[(sto) + i0 * 8]);                    \
    gl_lds16(arow1 + ko_, &lds[(sto) + i1 * 8]);                    \
    gl_lds16((BP) + ko_, &lds[(sto) + 8192 + tid * 8]);             \
} while (0)

    floatx4 acc[4][4] = {};
    floatx4 acc512[4] = {};

    // prologue: w512 (duplicate-DMA across waves, benign) + pass-0 tiles
    // koff,koff+1 -> bufs 0,1. 2+3+3 issues; vmcnt(3) => w512 + tile-koff landed.
    gl_lds16(basisb + ((size_t)1024 << 10) + lane * 8, &w512l[lane * 8]);
    gl_lds16(basisb + ((size_t)1024 << 10) + 512 + lane * 8, &w512l[512 + lane * 8]);
    STAGE(koff, 0, brow0); STAGE(koff + 1, LBUF, brow0);
    asm volatile("s_waitcnt vmcnt(3)" ::: "memory");

    #pragma unroll 1
    for (int pass = 0; pass < 2; ++pass) {
        const unsigned short* browp = brow0 + (size_t)pass * 256 * HOP;

        int rdo = 0, sto = 2 * LBUF;
        #pragma unroll 1
        for (int tt = 0; tt < NKT; ++tt) {
            __builtin_amdgcn_s_barrier();
            int kk = tt + koff + 2;                     // stage distance-2 ahead
            if (kk >= NKT) kk -= NKT;
            if (kk >= NKT) kk -= NKT;                   // tail wraps: staged, never read
            STAGE(kk, sto, browp);

            bf16x8 af[4], bf[4];
            const unsigned short* pa = &lds[rdo + (wm * 64 + r0) * 32 + ce];
            const unsigned short* pb = &lds[rdo + 8192 + (wn * 64 + r0) * 32 + ce];
            #pragma unroll
            for (int mt = 0; mt < 4; ++mt) af[mt] = *(const bf16x8*)(pa + mt * 512);
            #pragma unroll
            for (int nt = 0; nt < 4; ++nt) bf[nt] = *(const bf16x8*)(pb + nt * 512);

            __builtin_amdgcn_s_setprio(1);
            #pragma unroll
            for (int mt = 0; mt < 4; ++mt)
                #pragma unroll
                for (int nt = 0; nt < 4; ++nt)
                    acc[mt][nt] = __builtin_amdgcn_mfma_f32_16x16x32_bf16(
                        af[mt], bf[nt], acc[mt][nt], 0, 0, 0);
            __builtin_amdgcn_s_setprio(0);

            if (do512) {                                // wave-uniform branch
                int cur = tt + koff; if (cur >= NKT) cur -= NKT;
                bf16x8 aw = {};
                if (r0 == 0)                            // A row 0 = w512, rows 1..15 = 0
                    aw = *(const bf16x8*)(&w512l[KT0 + cur * 32 + quad * 8]);
                #pragma unroll
                for (int nt = 0; nt < 4; ++nt)
                    acc512[nt] = __builtin_amdgcn_mfma_f32_16x16x32_bf16(
                        aw, bf[nt], acc512[nt], 0, 0, 0);
            }

            asm volatile("s_waitcnt vmcnt(3)" ::: "memory");
            rdo += LBUF; if (rdo == 3 * LBUF) rdo = 0;
            sto += LBUF; if (sto == 3 * LBUF) sto = 0;
        }

        // ---- pass transition / epilogue ----
        __builtin_amdgcn_s_barrier();                    // all frag reads done
        asm volatile("s_waitcnt vmcnt(0)" ::: "memory"); // wrap garbage landed
        if (pass == 0) {                                 // restage bufs 0,1 for pass 1
            const unsigned short* brown = brow0 + (size_t)256 * HOP;
            STAGE(koff, 0, brown); STAGE(koff + 1, LBUF, brown);
        }

        // stores: rows are interleaved (cos,sin) pairs -> coalesced float2
        const int mb = mg0 + wm * 64 + quad * 4;      // even
        const int fb = fg0 + pass * 256 + wn * 64 + r0;
        #pragma unroll
        for (int nt = 0; nt < 4; ++nt) {
            const int f = fb + nt * 16;
            if (f >= FRAMES) continue;
            #pragma unroll
            for (int mt = 0; mt < 4; ++mt) {
                const int mrow = mb + mt * 16;
                const floatx4 v = acc[mt][nt];
                #pragma unroll
                for (int p = 0; p < 2; ++p) {
                    const int bin = (mrow + 2 * p) >> 1;
                    float2 val;
                    val.x = v[2 * p];      // cos
                    val.y = v[2 * p + 1];  // sin
                    *(float2*)(out + (((size_t)b * NBINS + bin) * FRAMES + f) * 2) = val;
                }
            }
        }
        // bin512: output row 0 lives in quad==0 lanes, reg 0, col=r0
        if (do512 && quad == 0) {
            #pragma unroll
            for (int nt = 0; nt < 4; ++nt) {
                const int f = fb + nt * 16;
                if (f < FRAMES) {
                    float2 val; val.x = acc512[nt][0]; val.y = 0.f;
                    *(float2*)(out + (((size_t)b * NBINS + 512) * FRAMES + f) * 2) = val;
                }
            }
        }

        // reset accumulators for pass 1
        #pragma unroll
        for (int mt = 0; mt < 4; ++mt)
            #pragma unroll
            for (int nt = 0; nt < 4; ++nt) acc[mt][nt] = floatx4{0.f, 0.f, 0.f, 0.f};
        #pragma unroll
        for (int nt = 0; nt < 4; ++nt) acc512[nt] = floatx4{0.f, 0.f, 0.f, 0.f};

        asm volatile("s_waitcnt vmcnt(0)" ::: "memory"); // restage + my stores landed
        __builtin_amdgcn_s_barrier();                    // all waves' restage landed
    }
#undef STAGE
}

extern "C" void kernel_launch(void* const* d_in, const int* in_sizes, int n_in,
                              void* d_out, int out_size, void* d_ws, size_t ws_size,
                              hipStream_t stream) {
    const float* x     = (const float*)d_in[0];
    const float* basis = (const float*)d_in[1];
    float* out         = (float*)d_out;

    unsigned short* basis_bf = (unsigned short*)d_ws;
    unsigned short* xp_bf    = (unsigned short*)d_ws + WS_XP_OFF;

    stft_prep<<<dim3(PREP_BLOCKS), dim3(256), 0, stream>>>(x, basis, basis_bf, xp_bf, out);

    // batch fastest -> XCD = b%8 (per-XCD: full A 2MB + 4 batches' xp 1.3MB < L2).
    // 256 persistent blocks (1/CU, 74KB LDS); each handles fg0 and fg0+256.
    dim3 grid(B_SZ, 2, 4);   // batches x 2 frame-tile-pairs x 4 row-tiles
    stft_mfma_kernel<<<grid, dim3(512), 0, stream>>>(basis_bf, xp_bf, out);
}

// Round 9
// 117.370 us; speedup vs baseline: 1.1128x; 1.1128x over previous
//
#include <hip/hip_runtime.h>

#define B_SZ   32
#define T_LEN  160000
#define NFFT   1024
#define HOP    320
#define FRAMES 501
#define NBINS  513
#define PADL   512

#define XP_STRIDE 164864                  // padded per-batch xp length (elements)
#define WS_XP_OFF (1025 * NFFT)           // ushort-element offset of xp region in ws
#define XP_G8_PB  (XP_STRIDE / 8)         // 20608 8-elem groups per batch

// prep-kernel block ranges: [0,512) basis rows 0..1023 | 512: w512 row | xp convert
#define PB_BASIS  512
#define PB_XP     2576
#define PREP_BLOCKS (PB_BASIS + 1 + PB_XP)

// K-trim: Hann window (WIN=800) is zero outside k in [112,912) -> basis cols
// there are exactly 0.0. Cover with 64-aligned range [96,928): 13 tiles of 64.
#define KT0  96
#define NT64 13

typedef __bf16 bf16x8  __attribute__((ext_vector_type(8)));
typedef float  floatx4 __attribute__((ext_vector_type(4)));

__device__ __forceinline__ unsigned short f2bf(float f) {
    unsigned u = __builtin_bit_cast(unsigned, f);
    u += 0x7FFFu + ((u >> 16) & 1u);      // round-to-nearest-even
    return (unsigned short)(u >> 16);
}

__device__ __forceinline__ void gl_lds16(const void* g, void* l) {
    __builtin_amdgcn_global_load_lds(
        (const __attribute__((address_space(1))) unsigned int*)g,
        (__attribute__((address_space(3))) unsigned int*)l, 16, 0, 0);
}

// ---- prep: pure-bandwidth converts only (bin512 computed inside the GEMM) ----
__global__ void stft_prep(const float* __restrict__ x,
                          const float* __restrict__ basis,
                          unsigned short* __restrict__ basisb,
                          unsigned short* __restrict__ xpb,
                          float* __restrict__ out) {
    const int blk = blockIdx.x;
    const int tid = threadIdx.x;

    if (blk < PB_BASIS) {
        const int gid = blk * 256 + tid;          // 8 elems per thread, exact cover
        const int row = gid >> 7;                 // 0..1023
        const int col = (gid & 127) * 8;
        const int j = row >> 1, c = row & 1;
        const float* src = basis + (size_t)(j + c * NBINS) * NFFT + col;
        const float4 v0 = *(const float4*)(src);
        const float4 v1 = *(const float4*)(src + 4);
        ushort4 o0, o1;
        o0.x = f2bf(v0.x); o0.y = f2bf(v0.y); o0.z = f2bf(v0.z); o0.w = f2bf(v0.w);
        o1.x = f2bf(v1.x); o1.y = f2bf(v1.y); o1.z = f2bf(v1.z); o1.w = f2bf(v1.w);
        unsigned short* d = basisb + ((size_t)row << 10) + col;
        *(ushort4*)(d)     = o0;
        *(ushort4*)(d + 4) = o1;
    } else if (blk == PB_BASIS) {
        // w512 row: bf16 of basis row 512 (windowed cos_512); 256 thr x 4 elems
        const float4 v = *(const float4*)(basis + (size_t)512 * NFFT + tid * 4);
        ushort4 o;
        o.x = f2bf(v.x); o.y = f2bf(v.y); o.z = f2bf(v.z); o.w = f2bf(v.w);
        *(ushort4*)(basisb + ((size_t)1024 << 10) + tid * 4) = o;
    } else {
        const int i   = (blk - PB_BASIS - 1) * 256 + tid;   // 0..659455, exact cover
        const int b   = i / XP_G8_PB;
        const int pos = (i - b * XP_G8_PB) * 8;         // boundaries (512,160512) are %8==0
        ushort4 o0 = {0,0,0,0}, o1 = {0,0,0,0};
        if (pos >= PADL && pos < T_LEN + PADL) {
            const float* src = x + (size_t)b * T_LEN + (pos - PADL);
            const float4 v0 = *(const float4*)(src);
            const float4 v1 = *(const float4*)(src + 4);
            o0.x = f2bf(v0.x); o0.y = f2bf(v0.y); o0.z = f2bf(v0.z); o0.w = f2bf(v0.w);
            o1.x = f2bf(v1.x); o1.y = f2bf(v1.y); o1.z = f2bf(v1.z); o1.w = f2bf(v1.w);
        }
        unsigned short* d = xpb + (size_t)b * XP_STRIDE + pos;
        *(ushort4*)(d)     = o0;
        *(ushort4*)(d + 4) = o1;
    }
}

// ---- MFMA GEMM v9 = the R2-proven deep pipeline (best per-FLOP: 676 TF)
// + K-trim (13 tiles of 64) + fused bin512 (proven R7).
// 256x256 tile, 8 waves (2M x 4N -> 128x64/wave), BK=64 as 2x32 halves,
// 2 x 64KB LDS buffers, 4 phases per K-tile, counted vmcnt(8) (never 0
// in-loop), XOR-swizzled conflict-free LDS, grid (b,y,z)=batch-fastest
// (XCD = b%8, per-XCD footprint 3.3MB < L2 -> FETCH was 13.4MB, perfect).
// Odd tile count: generic tile body with runtime buffer offset ro=(t&1)*32K;
// staging ledger is position-invariant: tile t stages A1/B1(t+1)->other buf
// (parts whose last reads drained >=1 barrier earlier), A0/B0(t+2)->own buf;
// vmcnt(8) after p2 guarantees kh1(t) resident, after p4 kh0(t+1) resident.
// WRAP13 garbage staging at the tail: valid addresses, never read, drained
// by the final vmcnt(0).
// bin512: w512 staged in prologue (14 issues; vmcnt(8) drains w512+A0(0)+B0(0));
// per phase the wm==0 waves of mg0==0 blocks add 2 MFMA with
// A = (r0==0 ? w512[KT0 + t*64 + kh*32 + quad*8] : 0) against bf[0..1].
__launch_bounds__(512, 2)
__global__ void stft_mfma_kernel(const unsigned short* __restrict__ basisb,
                                 const unsigned short* __restrict__ xpb,
                                 float* __restrict__ out) {
    __shared__ unsigned short lds[65536];    // 128 KB: 2 bufs x 4 parts x 8192
    __shared__ unsigned short w512l[1024];   // w512 row, global k in [0,1024)

    const int tid  = threadIdx.x;
    const int lane = tid & 63;
    const int w    = tid >> 6;        // wave 0..7
    const int wm   = w & 1;           // m-half of 256 (128 rows)
    const int wn   = w >> 1;          // n-quarter of 256 (64 frames)
    const int r0   = lane & 15;
    const int quad = lane >> 4;
    // swizzled 16B-slot within a 64-B row: slot = quad ^ ((row>>1)&3)
    const int ce   = (quad ^ ((r0 >> 1) & 3)) * 8;

    const int b   = blockIdx.x;                 // batch fastest -> XCD = b%8
    const int fg0 = blockIdx.y * 256;           // frame tile base (0,256)
    const int mg0 = blockIdx.z * 256;           // row tile base (0..768)
    const unsigned short* xpbb = xpb + (size_t)b * XP_STRIDE;
    const bool do512 = (mg0 == 0) && (wm == 0); // wave-uniform

    // staging: each half-tile (A or B, 256 rows x 32 k = 16 KB) = 2 issues/thread.
    // LDS dest linear; global source column pre-swizzled (same involution as reads).
    const int i0 = tid, i1 = 512 + tid;
    const int row0 = i0 >> 2, row1 = i1 >> 2;          // 0..127, 128..255
    const int cs0 = ((i0 & 3) ^ ((row0 >> 1) & 3)) * 8;
    const int cs1 = ((i1 & 3) ^ ((row1 >> 1) & 3)) * 8;
    const unsigned short* arow0 = basisb + ((size_t)(mg0 + row0) << 10) + cs0;
    const unsigned short* arow1 = basisb + ((size_t)(mg0 + row1) << 10) + cs1;
    const unsigned short* brow0 = xpbb + (size_t)(fg0 + row0) * HOP + cs0;
    const unsigned short* brow1 = xpbb + (size_t)(fg0 + row1) * HOP + cs1;

#define WRAP13(x) ((x) >= NT64 ? (x) - NT64 : (x))
#define STAGE_A(kt, kh, bo) do {                                    \
    const int ko_ = KT0 + (kt) * 64 + (kh) * 32;                    \
    gl_lds16(arow0 + ko_, &lds[(bo) + (kh) * 8192 + i0 * 8]);       \
    gl_lds16(arow1 + ko_, &lds[(bo) + (kh) * 8192 + i1 * 8]);       \
} while (0)
#define STAGE_B(kt, kh, bo) do {                                    \
    const int ko_ = KT0 + (kt) * 64 + (kh) * 32;                    \
    gl_lds16(brow0 + ko_, &lds[(bo) + (2 + (kh)) * 8192 + i0 * 8]); \
    gl_lds16(brow1 + ko_, &lds[(bo) + (2 + (kh)) * 8192 + i1 * 8]); \
} while (0)

    floatx4 acc[8][4] = {};
    floatx4 acc512[4] = {};
    bf16x8 af[8], bf[2];

#define LOAD_A(kh, ro) do {                                                   \
    const unsigned short* pa_ =                                               \
        &lds[(ro) + (kh) * 8192 + (wm * 128 + r0) * 32 + ce];                 \
    _Pragma("unroll")                                                         \
    for (int mt = 0; mt < 8; ++mt) af[mt] = *(const bf16x8*)(pa_ + mt * 512); \
} while (0)
#define LOAD_B(kh, nh, ro) do {                                               \
    const unsigned short* pb_ =                                               \
        &lds[(ro) + (2 + (kh)) * 8192 + (wn * 64 + (nh) * 32 + r0) * 32 + ce];\
    bf[0] = *(const bf16x8*)(pb_);                                            \
    bf[1] = *(const bf16x8*)(pb_ + 512);                                      \
} while (0)
#define MFMA16(nh) do {                                                       \
    _Pragma("unroll")                                                         \
    for (int mt = 0; mt < 8; ++mt) {                                          \
        acc[mt][(nh) * 2]     = __builtin_amdgcn_mfma_f32_16x16x32_bf16(      \
            af[mt], bf[0], acc[mt][(nh) * 2], 0, 0, 0);                       \
        acc[mt][(nh) * 2 + 1] = __builtin_amdgcn_mfma_f32_16x16x32_bf16(      \
            af[mt], bf[1], acc[mt][(nh) * 2 + 1], 0, 0, 0);                   \
    }                                                                         \
} while (0)
#define VMC8 asm volatile("s_waitcnt vmcnt(8)" ::: "memory")
#define PHASE(kh, nh, DO_STAGE, DO_VM) do {                                   \
    if ((nh) == 0) { LOAD_A(kh, ro); }                                        \
    LOAD_B(kh, nh, ro);                                                       \
    DO_STAGE;                                                                 \
    __builtin_amdgcn_s_barrier();                                             \
    asm volatile("s_waitcnt lgkmcnt(0)" ::: "memory");                        \
    __builtin_amdgcn_s_setprio(1);                                            \
    MFMA16(nh);                                                               \
    if (do512) {                                  /* wave-uniform */          \
        bf16x8 aw = {};                                                       \
        if (r0 == 0)  /* A row 0 = w512, rows 1..15 = 0 */                    \
            aw = *(const bf16x8*)(&w512l[KT0 + t * 64 + (kh) * 32 + quad * 8]);\
        acc512[(nh) * 2]     = __builtin_amdgcn_mfma_f32_16x16x32_bf16(       \
            aw, bf[0], acc512[(nh) * 2], 0, 0, 0);                            \
        acc512[(nh) * 2 + 1] = __builtin_amdgcn_mfma_f32_16x16x32_bf16(       \
            aw, bf[1], acc512[(nh) * 2 + 1], 0, 0, 0);                        \
    }                                                                         \
    __builtin_amdgcn_s_setprio(0);                                            \
    DO_VM;                                                                    \
    __builtin_amdgcn_s_barrier();                                             \
} while (0)

    // prologue: w512 (2) then A0(0) B0(0) A1(0) B1(0) -> buf0, A0(1) B0(1) -> buf1
    // = 14 issues; vmcnt(8) drains the oldest 6 = w512 + A0(0) + B0(0).
    gl_lds16(basisb + ((size_t)1024 << 10) + lane * 8, &w512l[lane * 8]);
    gl_lds16(basisb + ((size_t)1024 << 10) + 512 + lane * 8, &w512l[512 + lane * 8]);
    STAGE_A(0, 0, 0); STAGE_B(0, 0, 0);
    STAGE_A(0, 1, 0); STAGE_B(0, 1, 0);
    STAGE_A(1, 0, 32768); STAGE_B(1, 0, 32768);
    VMC8;
    __builtin_amdgcn_s_barrier();

    #pragma unroll 1
    for (int t = 0; t < NT64; ++t) {
        const int ro = (t & 1) * 32768;             // buffer holding tile t
        const int so = ro ^ 32768;                  // buffer of tile t+1
        PHASE(0, 0, STAGE_A(WRAP13(t + 1), 1, so), );
        PHASE(0, 1, STAGE_B(WRAP13(t + 1), 1, so), VMC8);
        PHASE(1, 0, STAGE_A(WRAP13(t + 2), 0, ro), );
        PHASE(1, 1, STAGE_B(WRAP13(t + 2), 0, ro), VMC8);
    }
    // drain wrap-around garbage LDS-DMA before LDS is freed
    asm volatile("s_waitcnt vmcnt(0)" ::: "memory");

    // epilogue: rows are interleaved (cos,sin) pairs -> coalesced float2 stores
    const int mb = mg0 + wm * 128 + quad * 4;     // even
    const int fb = fg0 + wn * 64 + r0;
    #pragma unroll
    for (int nt = 0; nt < 4; ++nt) {
        const int f = fb + nt * 16;
        if (f >= FRAMES) continue;
        #pragma unroll
        for (int mt = 0; mt < 8; ++mt) {
            const int mrow = mb + mt * 16;
            const floatx4 v = acc[mt][nt];
            #pragma unroll
            for (int p = 0; p < 2; ++p) {
                const int bin = (mrow + 2 * p) >> 1;
                float2 val;
                val.x = v[2 * p];      // cos
                val.y = v[2 * p + 1];  // sin
                *(float2*)(out + (((size_t)b * NBINS + bin) * FRAMES + f) * 2) = val;
            }
        }
    }
    // bin512: output row 0 lives in quad==0 lanes, reg 0, col=r0
    if (do512 && quad == 0) {
        #pragma unroll
        for (int nt = 0; nt < 4; ++nt) {
            const int f = fb + nt * 16;
            if (f < FRAMES) {
                float2 val; val.x = acc512[nt][0]; val.y = 0.f;
                *(float2*)(out + (((size_t)b * NBINS + 512) * FRAMES + f) * 2) = val;
            }
        }
    }
#undef WRAP13
#undef STAGE_A
#undef STAGE_B
#undef LOAD_A
#undef LOAD_B
#undef MFMA16
#undef VMC8
#undef PHASE
}

extern "C" void kernel_launch(void* const* d_in, const int* in_sizes, int n_in,
                              void* d_out, int out_size, void* d_ws, size_t ws_size,
                              hipStream_t stream) {
    const float* x     = (const float*)d_in[0];
    const float* basis = (const float*)d_in[1];
    float* out         = (float*)d_out;

    unsigned short* basis_bf = (unsigned short*)d_ws;
    unsigned short* xp_bf    = (unsigned short*)d_ws + WS_XP_OFF;

    stft_prep<<<dim3(PREP_BLOCKS), dim3(256), 0, stream>>>(x, basis, basis_bf, xp_bf, out);

    // batch fastest -> XCD = b%8: per-XCD footprint = A 2MB + 4 batches' xp
    // 1.3MB < 4MB L2 (R2-measured FETCH 13.4MB = compulsory).
    dim3 grid(B_SZ, 2, 4);   // 256 blocks (1/CU, 130KB LDS)
    stft_mfma_kernel<<<grid, dim3(512), 0, stream>>>(basis_bf, xp_bf, out);
}